// Round 6
// baseline (877.781 us; speedup 1.0000x reference)
//
#include <hip/hip_runtime.h>
#include <hip/hip_bf16.h>
#include <math.h>

#define DIMC 768
#define NHEADS 12
#define WINSZ 14
#define NTOK 196
#define TOKENS 16384

using bf = __hip_bfloat16;
typedef __attribute__((ext_vector_type(4))) float f32x4;
typedef __attribute__((ext_vector_type(8))) short bf16x8;

typedef __attribute__((address_space(3))) void lds_void_t;
typedef const __attribute__((address_space(1))) void gmem_void_t;

__device__ inline float bfu2f(ushort u) { return __uint_as_float((uint)u << 16); }
__device__ inline ushort f2bu(float f) {
    bf t = __float2bfloat16(f);
    return __builtin_bit_cast(ushort, t);
}

// ---------------- weight transpose + fp32 -> bf16 convert (tiny) ----------------
__global__ __launch_bounds__(256) void transpose_k(const float* __restrict__ in,
                                                   ushort* __restrict__ out, int R, int C) {
    long i = (long)blockIdx.x * 256 + threadIdx.x;
    if (i >= (long)R * C) return;
    int r = (int)(i / C), c = (int)(i % C);
    out[(long)c * R + r] = f2bu(in[i]);
}

// ---------------- layernorm fp32 in, bf16 out ----------------
__device__ inline float blk_sum(float v, float* wred, int tid) {
    for (int m = 32; m; m >>= 1) v += __shfl_xor(v, m);
    if ((tid & 63) == 0) wred[tid >> 6] = v;
    __syncthreads();
    float r = wred[0] + wred[1] + wred[2] + wred[3];
    __syncthreads();
    return r;
}

__global__ __launch_bounds__(256) void ln_k(const float* __restrict__ x, const float* __restrict__ g,
                                            const float* __restrict__ bb, ushort* __restrict__ out) {
    int row = blockIdx.x, tid = threadIdx.x;
    const float* xr = x + (size_t)row * DIMC;
    __shared__ float wred[4];
    float v0 = xr[tid], v1 = xr[tid + 256], v2 = xr[tid + 512];
    float mean = blk_sum(v0 + v1 + v2, wred, tid) * (1.f / 768.f);
    float d0 = v0 - mean, d1 = v1 - mean, d2 = v2 - mean;
    float var = blk_sum(d0 * d0 + d1 * d1 + d2 * d2, wred, tid) * (1.f / 768.f);
    float rs = rsqrtf(var + 1e-5f);
    ushort* o = out + (size_t)row * DIMC;
    o[tid]       = f2bu(d0 * rs * g[tid]       + bb[tid]);
    o[tid + 256] = f2bu(d1 * rs * g[tid + 256] + bb[tid + 256]);
    o[tid + 512] = f2bu(d2 * rs * g[tid + 512] + bb[tid + 512]);
}

// ---------------- bf16 MFMA GEMM: 256x128 tile, BK=32, 4 waves, wave-tile 128x64 ----
// M mult of 256, N mult of 128, K mult of 32. Bt pre-transposed [N][K] bf16.
// Wave-tile 128x64 cuts LDS read bytes/FLOP by 1.33x vs 64x64 (R5 analysis: LDS BW +
// barrier serialization bound the old structure). Schedule unchanged (proven 2-phase
// dbuf prefetch, one barrier per K-step). T2 slot-XOR swizzle reused verbatim
// (per-32-col-row property, geometry independent). T1 XCD swizzle: grids all %8==0.
// LDS 48KB + VGPR<=256 (launch_bounds(256,2)) -> 2 blocks/CU.
enum { EPI_BIAS = 0, EPI_GELU = 1, EPI_PROJRES = 2, EPI_ACC = 3, EPI_RESOUT = 4 };

template <int EPI>
__global__ __launch_bounds__(256, 2) void gemm_k(const ushort* __restrict__ A, int lda,
                                                 const ushort* __restrict__ Bt, int ldb,
                                                 const float* __restrict__ bias,
                                                 ushort* __restrict__ outb,
                                                 float* __restrict__ outf,
                                                 const float* __restrict__ xorig,
                                                 float* __restrict__ x2,
                                                 int N, int K) {
    __shared__ ushort lA[2][256 * 32];   // 16 KB per buf
    __shared__ ushort lB[2][128 * 32];   // 8 KB per buf

    const int nwg = gridDim.x * gridDim.y;
    const int l = blockIdx.y * gridDim.x + blockIdx.x;
    const int nl = (l & 7) * (nwg >> 3) + (l >> 3);
    const int bx = nl % gridDim.x, by = nl / gridDim.x;
    const int bm = by * 256, bn = bx * 128;

    const int tid = threadIdx.x, wave = tid >> 6, lane = tid & 63;
    const int wy = wave >> 1, wx = wave & 1;      // 2M x 2N wave grid
    const int lm = lane & 15, quad = lane >> 4;

    f32x4 acc[8][4];
#pragma unroll
    for (int r = 0; r < 8; ++r)
#pragma unroll
        for (int s = 0; s < 4; ++s) acc[r][s] = (f32x4){0.f, 0.f, 0.f, 0.f};

    // chunk = 16 rows x 32 cols = 1 KB; lane l -> row l>>2, LDS byte l*16 (linear).
    // Source col group XOR-permuted: LDS slot (row,g) holds global group g^((row>>1)&3).
    const int srcg = (lane & 3) ^ ((lane >> 3) & 3);
    const ushort* Ab = A + (size_t)(bm + (lane >> 2)) * lda + srcg * 8;
    const ushort* Bb = Bt + (size_t)(bn + (lane >> 2)) * ldb + srcg * 8;
    const size_t a16 = (size_t)16 * lda, b16 = (size_t)16 * ldb;
    const int ca = wave * 4;   // A chunks ca..ca+3 (16 chunks over 4 waves)
    const int cb = wave * 2;   // B chunks cb..cb+1 (8 chunks)

    auto stage = [&](int bi, int k0) {
#pragma unroll
        for (int j = 0; j < 4; ++j)
            __builtin_amdgcn_global_load_lds((gmem_void_t*)(Ab + (size_t)(ca + j) * a16 + k0),
                                             (lds_void_t*)&lA[bi][(ca + j) * 512], 16, 0, 0);
#pragma unroll
        for (int j = 0; j < 2; ++j)
            __builtin_amdgcn_global_load_lds((gmem_void_t*)(Bb + (size_t)(cb + j) * b16 + k0),
                                             (lds_void_t*)&lB[bi][(cb + j) * 512], 16, 0, 0);
    };

    const int rg = (quad ^ ((lm >> 1) & 3)) * 8;   // swizzled group for this lane's rows
    const int nt = K >> 5;

    stage(0, 0);
    __syncthreads();

    for (int t = 0; t < nt; ++t) {
        const int cur = t & 1;
        if (t + 1 < nt) stage(cur ^ 1, (t + 1) * 32);   // prefetch flies under compute

        bf16x8 af[8], bv[4];
#pragma unroll
        for (int r = 0; r < 8; ++r)
            af[r] = *(const bf16x8*)&lA[cur][(wy * 128 + r * 16 + lm) * 32 + rg];
#pragma unroll
        for (int s = 0; s < 4; ++s)
            bv[s] = *(const bf16x8*)&lB[cur][(wx * 64 + s * 16 + lm) * 32 + rg];
#pragma unroll
        for (int r = 0; r < 8; ++r)
#pragma unroll
            for (int s = 0; s < 4; ++s)
                acc[r][s] = __builtin_amdgcn_mfma_f32_16x16x32_bf16(af[r], bv[s], acc[r][s], 0, 0, 0);
        __syncthreads();   // drains prefetch (vmcnt 0) + WAR protection
    }

#pragma unroll
    for (int s = 0; s < 4; ++s) {
        int col = bn + wx * 64 + s * 16 + lm;
        float bvl = (EPI == EPI_ACC) ? 0.f : bias[col];
#pragma unroll
        for (int r = 0; r < 8; ++r) {
#pragma unroll
            for (int i = 0; i < 4; ++i) {
                int row = bm + wy * 128 + r * 16 + quad * 4 + i;
                float v = acc[r][s][i] + bvl;
                size_t idx = (size_t)row * N + col;
                if constexpr (EPI == EPI_BIAS) {
                    outb[idx] = f2bu(v);
                } else if constexpr (EPI == EPI_GELU) {
                    outb[idx] = f2bu(0.5f * v * (1.f + erff(v * 0.70710678118f)));
                } else if constexpr (EPI == EPI_PROJRES) {
                    x2[idx] = xorig[idx] + v;
                } else if constexpr (EPI == EPI_ACC) {
                    x2[idx] += v;
                } else {
                    outf[idx] = x2[idx] + v;
                }
            }
        }
    }
}

// ---------------- MFMA attention: one block per (window, head), 4 waves (R3 proven) ----
__global__ __launch_bounds__(256) void attn_k(const ushort* __restrict__ qkv,
                                              const float* __restrict__ qkvb,
                                              const float* __restrict__ relh,
                                              const float* __restrict__ relw,
                                              ushort* __restrict__ aout) {
    const int win = blockIdx.x / NHEADS, head = blockIdx.x % NHEADS;
    const int b = win / 25, wi = win % 25, wr = wi / 5, wc = wi % 5;
    const int hmax = (wr == 4) ? 8 : WINSZ, wmax = (wc == 4) ? 8 : WINSZ;
    const int hoff = head * 64;
    const int tid = threadIdx.x, wave = tid >> 6, lane = tid & 63;
    const int c = lane & 15, quad = lane >> 4;

    __shared__ ushort Ksw[224 * 64];     // K raw (unscaled), chunk-XOR swizzled (28 KB)
    __shared__ ushort vTs[64 * 264];     // V^T, stride 264 + chunk-XOR swizzle (33 KB)
    __shared__ ushort wscr[4][640];      // per-wave scratch

    // ---- stage K: pure uint4 copy (scale applied in S epilogue) ----
    for (int t = tid; t < 224 * 8; t += 256) {
        int n = t >> 3, ck = t & 7;
        int kh = n >> 4, kw = n & 15;
        uint4 vals;
        if (kw < WINSZ && kh < hmax && kw < wmax) {
            size_t tok = ((size_t)(b * 64 + wr * WINSZ + kh) * 64 + wc * WINSZ + kw);
            vals = *(const uint4*)(qkv + tok * 2304 + 768 + hoff + ck * 8);
        } else if (kw < WINSZ) {  // pad token inside window: k = qkv bias slice
            union { uint4 u; ushort s[8]; } tmp;
#pragma unroll
            for (int j = 0; j < 8; ++j) tmp.s[j] = f2bu(qkvb[768 + hoff + ck * 8 + j]);
            vals = tmp.u;
        } else {
            vals = (uint4){0u, 0u, 0u, 0u};
        }
        *(uint4*)&Ksw[n * 64 + ((ck ^ (n & 7)) * 8)] = vals;
    }
    // ---- stage V^T: coalesced uint4 row reads + swizzled transposed LDS writes ----
    for (int t = tid; t < 224 * 8; t += 256) {
        int n = t >> 3, dg = t & 7;
        int kh = n >> 4, kw = n & 15;
        union { uint4 u; ushort s[8]; } vals;
        if (kw < WINSZ && kh < hmax && kw < wmax) {
            size_t tok = ((size_t)(b * 64 + wr * WINSZ + kh) * 64 + wc * WINSZ + kw);
            vals.u = *(const uint4*)(qkv + tok * 2304 + 1536 + hoff + dg * 8);
        } else if (kw < WINSZ) {
#pragma unroll
            for (int j = 0; j < 8; ++j) vals.s[j] = f2bu(qkvb[1536 + hoff + dg * 8 + j]);
        } else {
            vals.u = (uint4){0u, 0u, 0u, 0u};   // P=0 there; any finite value ok
        }
        int kchunk = n >> 3;
#pragma unroll
        for (int j = 0; j < 8; ++j) {
            int d = dg * 8 + j;
            vTs[d * 264 + ((kchunk ^ dg) * 8) + (n & 7)] = vals.s[j];
        }
    }
    __syncthreads();   // the ONLY block barrier

    bf16x8 rhB[2][2], rwB[2][2];
#pragma unroll
    for (int nt = 0; nt < 2; ++nt) {
        int j = nt * 16 + c; if (j > 26) j = 26;
#pragma unroll
        for (int ks = 0; ks < 2; ++ks) {
            const float* ph = relh + (size_t)j * 64 + ks * 32 + quad * 8;
            const float* pw = relw + (size_t)j * 64 + ks * 32 + quad * 8;
            bf16x8 h, w;
#pragma unroll
            for (int e = 0; e < 8; ++e) {
                h[e] = (short)f2bu(ph[e]);
                w[e] = (short)f2bu(pw[e]);
            }
            rhB[nt][ks] = h; rwB[nt][ks] = w;
        }
    }

    ushort* scr = &wscr[wave][0];
    const int lane48 = lane & 48;

    for (int qh = wave; qh < hmax; qh += 4) {
        int qw = c < wmax ? c : (wmax - 1);
        size_t qtok = ((size_t)(b * 64 + wr * WINSZ + qh) * 64 + wc * WINSZ + qw);
        bf16x8 aq0 = *(const bf16x8*)(qkv + qtok * 2304 + hoff + quad * 8);
        bf16x8 aq1 = *(const bf16x8*)(qkv + qtok * 2304 + hoff + 32 + quad * 8);

        f32x4 z = (f32x4){0.f, 0.f, 0.f, 0.f};
        f32x4 dh0 = __builtin_amdgcn_mfma_f32_16x16x32_bf16(aq0, rhB[0][0], z, 0, 0, 0);
        dh0 = __builtin_amdgcn_mfma_f32_16x16x32_bf16(aq1, rhB[0][1], dh0, 0, 0, 0);
        f32x4 dh1 = __builtin_amdgcn_mfma_f32_16x16x32_bf16(aq0, rhB[1][0], z, 0, 0, 0);
        dh1 = __builtin_amdgcn_mfma_f32_16x16x32_bf16(aq1, rhB[1][1], dh1, 0, 0, 0);
        f32x4 dw0 = __builtin_amdgcn_mfma_f32_16x16x32_bf16(aq0, rwB[0][0], z, 0, 0, 0);
        dw0 = __builtin_amdgcn_mfma_f32_16x16x32_bf16(aq1, rwB[0][1], dw0, 0, 0, 0);
        f32x4 dw1 = __builtin_amdgcn_mfma_f32_16x16x32_bf16(aq0, rwB[1][0], z, 0, 0, 0);
        dw1 = __builtin_amdgcn_mfma_f32_16x16x32_bf16(aq1, rwB[1][1], dw1, 0, 0, 0);

#pragma unroll
        for (int i = 0; i < 4; ++i) {
            scr[(quad * 4 + i) * 28 + c] = f2bu(dh0[i]);
            if (c < 12) scr[(quad * 4 + i) * 28 + 16 + c] = f2bu(dh1[i]);
        }

        float bw[4];
#pragma unroll
        for (int i = 0; i < 4; ++i) {
            int m = quad * 4 + i;
            int j = m - c + 13; int jc = j < 0 ? 0 : j;
            int addr = (lane48 | (jc & 15)) << 2;
            int t0 = __builtin_amdgcn_ds_bpermute(addr, __float_as_int(dw0[i]));
            int t1 = __builtin_amdgcn_ds_bpermute(addr, __float_as_int(dw1[i]));
            bw[i] = (jc >= 16) ? __int_as_float(t1) : __int_as_float(t0);
        }

        f32x4 s[14];
#pragma unroll
        for (int kh = 0; kh < 14; ++kh) {
            int n = kh * 16 + c;
            int n7 = n & 7;
            bf16x8 kb0 = *(const bf16x8*)&Ksw[n * 64 + ((0 * 4 + quad) ^ n7) * 8];
            bf16x8 kb1 = *(const bf16x8*)&Ksw[n * 64 + ((1 * 4 + quad) ^ n7) * 8];
            f32x4 acc = __builtin_amdgcn_mfma_f32_16x16x32_bf16(aq0, kb0, z, 0, 0, 0);
            acc = __builtin_amdgcn_mfma_f32_16x16x32_bf16(aq1, kb1, acc, 0, 0, 0);
            int jstar = qh + 13 - kh;
#pragma unroll
            for (int i = 0; i < 4; ++i) {
                float dh = bfu2f(scr[(quad * 4 + i) * 28 + jstar]);
                float v = fmaf(0.125f, acc[i], dh + bw[i]);
                acc[i] = (c < WINSZ) ? v : -1e30f;
            }
            s[kh] = acc;
        }

        float inv[4];
#pragma unroll
        for (int i = 0; i < 4; ++i) {
            float mx = s[0][i];
#pragma unroll
            for (int kh = 1; kh < 14; ++kh) mx = fmaxf(mx, s[kh][i]);
            mx = fmaxf(mx, __shfl_xor(mx, 1));
            mx = fmaxf(mx, __shfl_xor(mx, 2));
            mx = fmaxf(mx, __shfl_xor(mx, 4));
            mx = fmaxf(mx, __shfl_xor(mx, 8));
            float sum = 0.f;
#pragma unroll
            for (int kh = 0; kh < 14; ++kh) {
                float e = __expf(s[kh][i] - mx);
                s[kh][i] = e;
                sum += e;
            }
            sum += __shfl_xor(sum, 1);
            sum += __shfl_xor(sum, 2);
            sum += __shfl_xor(sum, 4);
            sum += __shfl_xor(sum, 8);
            inv[i] = 1.f / sum;
        }

        f32x4 o[4] = {z, z, z, z};
#pragma unroll
        for (int cc = 0; cc < 7; ++cc) {
#pragma unroll
            for (int i = 0; i < 4; ++i) {
                scr[(quad * 4 + i) * 40 + c]      = f2bu(s[2 * cc][i] * inv[i]);
                scr[(quad * 4 + i) * 40 + 16 + c] = f2bu(s[2 * cc + 1][i] * inv[i]);
            }
            bf16x8 ap = *(const bf16x8*)&scr[c * 40 + quad * 8];
#pragma unroll
            for (int vt = 0; vt < 4; ++vt) {
                int d = vt * 16 + c;
                int dgr = (d >> 3) & 7;
                bf16x8 vb = *(const bf16x8*)&vTs[d * 264 + (((cc * 4 + quad) ^ dgr) * 8)];
                o[vt] = __builtin_amdgcn_mfma_f32_16x16x32_bf16(ap, vb, o[vt], 0, 0, 0);
            }
        }

#pragma unroll
        for (int i = 0; i < 4; ++i) {
            int qwp = quad * 4 + i;
            if (qwp < wmax) {
                size_t otok = ((size_t)(b * 64 + wr * WINSZ + qh) * 64 + wc * WINSZ + qwp);
#pragma unroll
                for (int vt = 0; vt < 4; ++vt)
                    aout[otok * 768 + hoff + vt * 16 + c] = f2bu(o[vt][i]);
            }
        }
    }
}

extern "C" void kernel_launch(void* const* d_in, const int* in_sizes, int n_in,
                              void* d_out, int out_size, void* d_ws, size_t ws_size,
                              hipStream_t stream) {
    const float* x      = (const float*)d_in[0];
    const float* n1g    = (const float*)d_in[1];
    const float* n1b    = (const float*)d_in[2];
    const float* qkv_w  = (const float*)d_in[3];
    const float* qkv_b  = (const float*)d_in[4];
    const float* proj_w = (const float*)d_in[5];
    const float* proj_b = (const float*)d_in[6];
    const float* relh   = (const float*)d_in[7];
    const float* relw   = (const float*)d_in[8];
    const float* n2g    = (const float*)d_in[9];
    const float* n2b    = (const float*)d_in[10];
    const float* w1     = (const float*)d_in[11];
    const float* b1     = (const float*)d_in[12];
    const float* w2     = (const float*)d_in[13];
    const float* b2     = (const float*)d_in[14];
    float* out = (float*)d_out;

    char* ws = (char*)d_ws;
    size_t off = 0;
    auto alloc = [&](size_t bytes) -> void* {
        void* p = ws + off;
        off += (bytes + 255) & ~(size_t)255;
        return p;
    };

    ushort* lnbuf  = (ushort*)alloc((size_t)TOKENS * DIMC * 2);
    ushort* qkvbuf = (ushort*)alloc((size_t)TOKENS * 2304 * 2);
    float* x2      = (float*)alloc((size_t)TOKENS * DIMC * 4);
    ushort* qkvT   = (ushort*)alloc((size_t)2304 * 768 * 2);
    ushort* projT  = (ushort*)alloc((size_t)768 * 768 * 2);
    ushort* w1T    = (ushort*)alloc((size_t)3072 * 768 * 2);
    ushort* w2T    = (ushort*)alloc((size_t)768 * 3072 * 2);
    ushort* aout   = lnbuf;
    ushort* hc     = qkvbuf;

    transpose_k<<<(768 * 2304 + 255) / 256, 256, 0, stream>>>(qkv_w, qkvT, 768, 2304);
    transpose_k<<<(768 * 768 + 255) / 256, 256, 0, stream>>>(proj_w, projT, 768, 768);
    transpose_k<<<(768 * 3072 + 255) / 256, 256, 0, stream>>>(w1, w1T, 768, 3072);
    transpose_k<<<(3072 * 768 + 255) / 256, 256, 0, stream>>>(w2, w2T, 3072, 768);

    ln_k<<<TOKENS, 256, 0, stream>>>(x, n1g, n1b, lnbuf);

    dim3 gq(2304 / 128, TOKENS / 256);
    gemm_k<EPI_BIAS><<<gq, 256, 0, stream>>>(lnbuf, DIMC, qkvT, DIMC, qkv_b, qkvbuf,
                                             nullptr, nullptr, nullptr, 2304, DIMC);

    attn_k<<<100 * NHEADS, 256, 0, stream>>>(qkvbuf, qkv_b, relh, relw, aout);

    dim3 gp(DIMC / 128, TOKENS / 256);
    gemm_k<EPI_PROJRES><<<gp, 256, 0, stream>>>(aout, DIMC, projT, DIMC, proj_b, nullptr,
                                                nullptr, x, x2, DIMC, DIMC);

    ln_k<<<TOKENS, 256, 0, stream>>>(x2, n2g, n2b, lnbuf);

    dim3 gh(1536 / 128, TOKENS / 256);
    for (int c = 0; c < 2; ++c) {
        gemm_k<EPI_GELU><<<gh, 256, 0, stream>>>(lnbuf, DIMC, w1T + (size_t)c * 1536 * 768, DIMC,
                                                 b1 + c * 1536, hc, nullptr, nullptr, nullptr,
                                                 1536, DIMC);
        if (c == 0)
            gemm_k<EPI_ACC><<<gp, 256, 0, stream>>>(hc, 1536, w2T + (size_t)c * 1536, 3072,
                                                    b2, nullptr, nullptr, nullptr, x2, DIMC, 1536);
        else
            gemm_k<EPI_RESOUT><<<gp, 256, 0, stream>>>(hc, 1536, w2T + (size_t)c * 1536, 3072,
                                                       b2, nullptr, out, nullptr, x2, DIMC, 1536);
    }
}

// Round 7
// 660.936 us; speedup vs baseline: 1.3281x; 1.3281x over previous
//
#include <hip/hip_runtime.h>
#include <hip/hip_bf16.h>
#include <math.h>

#define DIMC 768
#define NHEADS 12
#define WINSZ 14
#define NTOK 196
#define TOKENS 16384

using bf = __hip_bfloat16;
typedef __attribute__((ext_vector_type(4))) float f32x4;
typedef __attribute__((ext_vector_type(8))) short bf16x8;

typedef __attribute__((address_space(3))) void lds_void_t;
typedef const __attribute__((address_space(1))) void gmem_void_t;

__device__ inline float bfu2f(ushort u) { return __uint_as_float((uint)u << 16); }
__device__ inline ushort f2bu(float f) {
    bf t = __float2bfloat16(f);
    return __builtin_bit_cast(ushort, t);
}

// ---------------- weight transpose + fp32 -> bf16 convert, LDS-tiled ----------------
// R, C multiples of 32. Coalesced reads AND writes (old version: 2B scattered writes,
// ~16x write amplification).
__global__ __launch_bounds__(256) void transpose_k(const float* __restrict__ in,
                                                   ushort* __restrict__ out, int R, int C) {
    __shared__ ushort tile[32][33];
    const int nbx = C >> 5;
    const int bx = blockIdx.x % nbx, by = blockIdx.x / nbx;
    const int tx = threadIdx.x & 31, ty = threadIdx.x >> 5;
#pragma unroll
    for (int p = 0; p < 4; ++p) {
        int r = by * 32 + ty + p * 8;
        tile[ty + p * 8][tx] = f2bu(in[(size_t)r * C + bx * 32 + tx]);
    }
    __syncthreads();
#pragma unroll
    for (int p = 0; p < 4; ++p) {
        int c = bx * 32 + ty + p * 8;
        out[(size_t)c * R + by * 32 + tx] = tile[tx][ty + p * 8];
    }
}

// ---------------- layernorm fp32 in, bf16 out ----------------
__device__ inline float blk_sum(float v, float* wred, int tid) {
    for (int m = 32; m; m >>= 1) v += __shfl_xor(v, m);
    if ((tid & 63) == 0) wred[tid >> 6] = v;
    __syncthreads();
    float r = wred[0] + wred[1] + wred[2] + wred[3];
    __syncthreads();
    return r;
}

__global__ __launch_bounds__(256) void ln_k(const float* __restrict__ x, const float* __restrict__ g,
                                            const float* __restrict__ bb, ushort* __restrict__ out) {
    int row = blockIdx.x, tid = threadIdx.x;
    const float* xr = x + (size_t)row * DIMC;
    __shared__ float wred[4];
    float v0 = xr[tid], v1 = xr[tid + 256], v2 = xr[tid + 512];
    float mean = blk_sum(v0 + v1 + v2, wred, tid) * (1.f / 768.f);
    float d0 = v0 - mean, d1 = v1 - mean, d2 = v2 - mean;
    float var = blk_sum(d0 * d0 + d1 * d1 + d2 * d2, wred, tid) * (1.f / 768.f);
    float rs = rsqrtf(var + 1e-5f);
    ushort* o = out + (size_t)row * DIMC;
    o[tid]       = f2bu(d0 * rs * g[tid]       + bb[tid]);
    o[tid + 256] = f2bu(d1 * rs * g[tid + 256] + bb[tid + 256]);
    o[tid + 512] = f2bu(d2 * rs * g[tid + 512] + bb[tid + 512]);
}

// ---------------- bf16 MFMA GEMM: 128x128 tile, counted-vmcnt half-step pipeline ----
// M,N multiples of 128; K multiple of 64. Bt pre-transposed [N][K] bf16.
// R3 geometry (proven) + T4: four BK=32 half-buffers (same 64KB LDS as R3's 2x BK=64),
// depth-3 ring. Per half-step: s_waitcnt vmcnt(8) (counted, NOT drain) + raw s_barrier
// + sched_barrier(0) (rule #18), ds_read frags, issue stage(h+3), 16 MFMA.
// WAR: buf (h+3)%4 == (h-1)%4 was consumed before barrier(h) (lgkm waits precede
// that iter's MFMAs). Worst case compiler adds its own drain -> degrades to R3 perf.
// T2 slot-XOR swizzle + T1 XCD swizzle unchanged.
enum { EPI_BIAS = 0, EPI_GELU = 1, EPI_PROJRES = 2, EPI_ACC = 3, EPI_RESOUT = 4 };

template <int EPI>
__global__ __launch_bounds__(256) void gemm_k(const ushort* __restrict__ A, int lda,
                                              const ushort* __restrict__ Bt, int ldb,
                                              const float* __restrict__ bias,
                                              ushort* __restrict__ outb,
                                              float* __restrict__ outf,
                                              const float* __restrict__ xorig,
                                              float* __restrict__ x2,
                                              int N, int K) {
    __shared__ ushort hA[4][128 * 32];   // 8 KB each: half-K ring buffers
    __shared__ ushort hB[4][128 * 32];

    const int nwg = gridDim.x * gridDim.y;
    const int l = blockIdx.y * gridDim.x + blockIdx.x;
    const int nl = (l & 7) * (nwg >> 3) + (l >> 3);
    const int bx = nl % gridDim.x, by = nl / gridDim.x;
    const int bm = by * 128, bn = bx * 128;

    const int tid = threadIdx.x, wave = tid >> 6, lane = tid & 63;
    const int wy = wave >> 1, wx = wave & 1;
    const int lm = lane & 15, quad = lane >> 4;

    f32x4 acc[4][4];
#pragma unroll
    for (int r = 0; r < 4; ++r)
#pragma unroll
        for (int s = 0; s < 4; ++s) acc[r][s] = (f32x4){0.f, 0.f, 0.f, 0.f};

    // chunk = 16 rows x 32 cols = 1KB; lane l -> row l>>2, LDS byte l*16 (linear).
    // Source col group XOR-permuted: LDS slot (row,g) holds global group g^((row>>1)&3).
    const int c0 = wave * 2, c1 = wave * 2 + 1;
    const int srcg = (lane & 3) ^ ((lane >> 3) & 3);
    const ushort* Ab = A + (size_t)(bm + (lane >> 2)) * lda + srcg * 8;
    const ushort* Bb = Bt + (size_t)(bn + (lane >> 2)) * ldb + srcg * 8;
    const size_t a16 = (size_t)16 * lda, b16 = (size_t)16 * ldb;

    auto stageH = [&](int bi, int k0) {   // 4 global_load_lds per wave
        __builtin_amdgcn_global_load_lds((gmem_void_t*)(Ab + (size_t)c0 * a16 + k0),
                                         (lds_void_t*)&hA[bi][c0 * 512], 16, 0, 0);
        __builtin_amdgcn_global_load_lds((gmem_void_t*)(Ab + (size_t)c1 * a16 + k0),
                                         (lds_void_t*)&hA[bi][c1 * 512], 16, 0, 0);
        __builtin_amdgcn_global_load_lds((gmem_void_t*)(Bb + (size_t)c0 * b16 + k0),
                                         (lds_void_t*)&hB[bi][c0 * 512], 16, 0, 0);
        __builtin_amdgcn_global_load_lds((gmem_void_t*)(Bb + (size_t)c1 * b16 + k0),
                                         (lds_void_t*)&hB[bi][c1 * 512], 16, 0, 0);
    };

    const int rg = (quad ^ ((lm >> 1) & 3)) * 8;   // swizzled group for this lane's rows
    const int H = K >> 5;                          // 32-col half-steps

    stageH(0, 0);
    if (H > 1) stageH(1, 32);
    if (H > 2) stageH(2, 64);

    for (int h = 0; h < H; ++h) {
        // wait until stage h has landed: outstanding own-wave loads are stages
        // h..min(h+2,H-1), 4 loads each; cross-wave visibility via the barrier
        // (all waves issue in lockstep order).
        if (h + 2 < H)      asm volatile("s_waitcnt vmcnt(8)" ::: "memory");
        else if (h + 1 < H) asm volatile("s_waitcnt vmcnt(4)" ::: "memory");
        else                asm volatile("s_waitcnt vmcnt(0)" ::: "memory");
        __builtin_amdgcn_s_barrier();
        __builtin_amdgcn_sched_barrier(0);

        const int bi = h & 3;
        bf16x8 af[4], bv[4];
#pragma unroll
        for (int r = 0; r < 4; ++r)
            af[r] = *(const bf16x8*)&hA[bi][(wy * 64 + r * 16 + lm) * 32 + rg];
#pragma unroll
        for (int s = 0; s < 4; ++s)
            bv[s] = *(const bf16x8*)&hB[bi][(wx * 64 + s * 16 + lm) * 32 + rg];

        if (h + 3 < H) stageH((h + 3) & 3, (h + 3) * 32);   // refill ring, depth 3

#pragma unroll
        for (int r = 0; r < 4; ++r)
#pragma unroll
            for (int s = 0; s < 4; ++s)
                acc[r][s] = __builtin_amdgcn_mfma_f32_16x16x32_bf16(af[r], bv[s], acc[r][s], 0, 0, 0);
    }

#pragma unroll
    for (int s = 0; s < 4; ++s) {
        int col = bn + wx * 64 + s * 16 + lm;
        float bvl = (EPI == EPI_ACC) ? 0.f : bias[col];
#pragma unroll
        for (int r = 0; r < 4; ++r) {
#pragma unroll
            for (int i = 0; i < 4; ++i) {
                int row = bm + wy * 64 + r * 16 + quad * 4 + i;
                float v = acc[r][s][i] + bvl;
                size_t idx = (size_t)row * N + col;
                if constexpr (EPI == EPI_BIAS) {
                    outb[idx] = f2bu(v);
                } else if constexpr (EPI == EPI_GELU) {
                    outb[idx] = f2bu(0.5f * v * (1.f + erff(v * 0.70710678118f)));
                } else if constexpr (EPI == EPI_PROJRES) {
                    x2[idx] = xorig[idx] + v;
                } else if constexpr (EPI == EPI_ACC) {
                    x2[idx] += v;
                } else {
                    outf[idx] = x2[idx] + v;
                }
            }
        }
    }
}

// ---------------- MFMA attention: one block per (window, head), 4 waves (R3 proven) ----
__global__ __launch_bounds__(256) void attn_k(const ushort* __restrict__ qkv,
                                              const float* __restrict__ qkvb,
                                              const float* __restrict__ relh,
                                              const float* __restrict__ relw,
                                              ushort* __restrict__ aout) {
    const int win = blockIdx.x / NHEADS, head = blockIdx.x % NHEADS;
    const int b = win / 25, wi = win % 25, wr = wi / 5, wc = wi % 5;
    const int hmax = (wr == 4) ? 8 : WINSZ, wmax = (wc == 4) ? 8 : WINSZ;
    const int hoff = head * 64;
    const int tid = threadIdx.x, wave = tid >> 6, lane = tid & 63;
    const int c = lane & 15, quad = lane >> 4;

    __shared__ ushort Ksw[224 * 64];     // K raw (unscaled), chunk-XOR swizzled (28 KB)
    __shared__ ushort vTs[64 * 264];     // V^T, stride 264 + chunk-XOR swizzle (33 KB)
    __shared__ ushort wscr[4][640];      // per-wave scratch

    // ---- stage K: pure uint4 copy (scale applied in S epilogue) ----
    for (int t = tid; t < 224 * 8; t += 256) {
        int n = t >> 3, ck = t & 7;
        int kh = n >> 4, kw = n & 15;
        uint4 vals;
        if (kw < WINSZ && kh < hmax && kw < wmax) {
            size_t tok = ((size_t)(b * 64 + wr * WINSZ + kh) * 64 + wc * WINSZ + kw);
            vals = *(const uint4*)(qkv + tok * 2304 + 768 + hoff + ck * 8);
        } else if (kw < WINSZ) {  // pad token inside window: k = qkv bias slice
            union { uint4 u; ushort s[8]; } tmp;
#pragma unroll
            for (int j = 0; j < 8; ++j) tmp.s[j] = f2bu(qkvb[768 + hoff + ck * 8 + j]);
            vals = tmp.u;
        } else {
            vals = (uint4){0u, 0u, 0u, 0u};
        }
        *(uint4*)&Ksw[n * 64 + ((ck ^ (n & 7)) * 8)] = vals;
    }
    // ---- stage V^T: coalesced uint4 row reads + swizzled transposed LDS writes ----
    for (int t = tid; t < 224 * 8; t += 256) {
        int n = t >> 3, dg = t & 7;
        int kh = n >> 4, kw = n & 15;
        union { uint4 u; ushort s[8]; } vals;
        if (kw < WINSZ && kh < hmax && kw < wmax) {
            size_t tok = ((size_t)(b * 64 + wr * WINSZ + kh) * 64 + wc * WINSZ + kw);
            vals.u = *(const uint4*)(qkv + tok * 2304 + 1536 + hoff + dg * 8);
        } else if (kw < WINSZ) {
#pragma unroll
            for (int j = 0; j < 8; ++j) vals.s[j] = f2bu(qkvb[1536 + hoff + dg * 8 + j]);
        } else {
            vals.u = (uint4){0u, 0u, 0u, 0u};   // P=0 there; any finite value ok
        }
        int kchunk = n >> 3;
#pragma unroll
        for (int j = 0; j < 8; ++j) {
            int d = dg * 8 + j;
            vTs[d * 264 + ((kchunk ^ dg) * 8) + (n & 7)] = vals.s[j];
        }
    }
    __syncthreads();   // the ONLY block barrier

    bf16x8 rhB[2][2], rwB[2][2];
#pragma unroll
    for (int nt = 0; nt < 2; ++nt) {
        int j = nt * 16 + c; if (j > 26) j = 26;
#pragma unroll
        for (int ks = 0; ks < 2; ++ks) {
            const float* ph = relh + (size_t)j * 64 + ks * 32 + quad * 8;
            const float* pw = relw + (size_t)j * 64 + ks * 32 + quad * 8;
            bf16x8 h, w;
#pragma unroll
            for (int e = 0; e < 8; ++e) {
                h[e] = (short)f2bu(ph[e]);
                w[e] = (short)f2bu(pw[e]);
            }
            rhB[nt][ks] = h; rwB[nt][ks] = w;
        }
    }

    ushort* scr = &wscr[wave][0];
    const int lane48 = lane & 48;

    for (int qh = wave; qh < hmax; qh += 4) {
        int qw = c < wmax ? c : (wmax - 1);
        size_t qtok = ((size_t)(b * 64 + wr * WINSZ + qh) * 64 + wc * WINSZ + qw);
        bf16x8 aq0 = *(const bf16x8*)(qkv + qtok * 2304 + hoff + quad * 8);
        bf16x8 aq1 = *(const bf16x8*)(qkv + qtok * 2304 + hoff + 32 + quad * 8);

        f32x4 z = (f32x4){0.f, 0.f, 0.f, 0.f};
        f32x4 dh0 = __builtin_amdgcn_mfma_f32_16x16x32_bf16(aq0, rhB[0][0], z, 0, 0, 0);
        dh0 = __builtin_amdgcn_mfma_f32_16x16x32_bf16(aq1, rhB[0][1], dh0, 0, 0, 0);
        f32x4 dh1 = __builtin_amdgcn_mfma_f32_16x16x32_bf16(aq0, rhB[1][0], z, 0, 0, 0);
        dh1 = __builtin_amdgcn_mfma_f32_16x16x32_bf16(aq1, rhB[1][1], dh1, 0, 0, 0);
        f32x4 dw0 = __builtin_amdgcn_mfma_f32_16x16x32_bf16(aq0, rwB[0][0], z, 0, 0, 0);
        dw0 = __builtin_amdgcn_mfma_f32_16x16x32_bf16(aq1, rwB[0][1], dw0, 0, 0, 0);
        f32x4 dw1 = __builtin_amdgcn_mfma_f32_16x16x32_bf16(aq0, rwB[1][0], z, 0, 0, 0);
        dw1 = __builtin_amdgcn_mfma_f32_16x16x32_bf16(aq1, rwB[1][1], dw1, 0, 0, 0);

#pragma unroll
        for (int i = 0; i < 4; ++i) {
            scr[(quad * 4 + i) * 28 + c] = f2bu(dh0[i]);
            if (c < 12) scr[(quad * 4 + i) * 28 + 16 + c] = f2bu(dh1[i]);
        }

        float bw[4];
#pragma unroll
        for (int i = 0; i < 4; ++i) {
            int m = quad * 4 + i;
            int j = m - c + 13; int jc = j < 0 ? 0 : j;
            int addr = (lane48 | (jc & 15)) << 2;
            int t0 = __builtin_amdgcn_ds_bpermute(addr, __float_as_int(dw0[i]));
            int t1 = __builtin_amdgcn_ds_bpermute(addr, __float_as_int(dw1[i]));
            bw[i] = (jc >= 16) ? __int_as_float(t1) : __int_as_float(t0);
        }

        f32x4 s[14];
#pragma unroll
        for (int kh = 0; kh < 14; ++kh) {
            int n = kh * 16 + c;
            int n7 = n & 7;
            bf16x8 kb0 = *(const bf16x8*)&Ksw[n * 64 + ((0 * 4 + quad) ^ n7) * 8];
            bf16x8 kb1 = *(const bf16x8*)&Ksw[n * 64 + ((1 * 4 + quad) ^ n7) * 8];
            f32x4 acc = __builtin_amdgcn_mfma_f32_16x16x32_bf16(aq0, kb0, z, 0, 0, 0);
            acc = __builtin_amdgcn_mfma_f32_16x16x32_bf16(aq1, kb1, acc, 0, 0, 0);
            int jstar = qh + 13 - kh;
#pragma unroll
            for (int i = 0; i < 4; ++i) {
                float dh = bfu2f(scr[(quad * 4 + i) * 28 + jstar]);
                float v = fmaf(0.125f, acc[i], dh + bw[i]);
                acc[i] = (c < WINSZ) ? v : -1e30f;
            }
            s[kh] = acc;
        }

        float inv[4];
#pragma unroll
        for (int i = 0; i < 4; ++i) {
            float mx = s[0][i];
#pragma unroll
            for (int kh = 1; kh < 14; ++kh) mx = fmaxf(mx, s[kh][i]);
            mx = fmaxf(mx, __shfl_xor(mx, 1));
            mx = fmaxf(mx, __shfl_xor(mx, 2));
            mx = fmaxf(mx, __shfl_xor(mx, 4));
            mx = fmaxf(mx, __shfl_xor(mx, 8));
            float sum = 0.f;
#pragma unroll
            for (int kh = 0; kh < 14; ++kh) {
                float e = __expf(s[kh][i] - mx);
                s[kh][i] = e;
                sum += e;
            }
            sum += __shfl_xor(sum, 1);
            sum += __shfl_xor(sum, 2);
            sum += __shfl_xor(sum, 4);
            sum += __shfl_xor(sum, 8);
            inv[i] = 1.f / sum;
        }

        f32x4 o[4] = {z, z, z, z};
#pragma unroll
        for (int cc = 0; cc < 7; ++cc) {
#pragma unroll
            for (int i = 0; i < 4; ++i) {
                scr[(quad * 4 + i) * 40 + c]      = f2bu(s[2 * cc][i] * inv[i]);
                scr[(quad * 4 + i) * 40 + 16 + c] = f2bu(s[2 * cc + 1][i] * inv[i]);
            }
            bf16x8 ap = *(const bf16x8*)&scr[c * 40 + quad * 8];
#pragma unroll
            for (int vt = 0; vt < 4; ++vt) {
                int d = vt * 16 + c;
                int dgr = (d >> 3) & 7;
                bf16x8 vb = *(const bf16x8*)&vTs[d * 264 + (((cc * 4 + quad) ^ dgr) * 8)];
                o[vt] = __builtin_amdgcn_mfma_f32_16x16x32_bf16(ap, vb, o[vt], 0, 0, 0);
            }
        }

#pragma unroll
        for (int i = 0; i < 4; ++i) {
            int qwp = quad * 4 + i;
            if (qwp < wmax) {
                size_t otok = ((size_t)(b * 64 + wr * WINSZ + qh) * 64 + wc * WINSZ + qwp);
#pragma unroll
                for (int vt = 0; vt < 4; ++vt)
                    aout[otok * 768 + hoff + vt * 16 + c] = f2bu(o[vt][i]);
            }
        }
    }
}

extern "C" void kernel_launch(void* const* d_in, const int* in_sizes, int n_in,
                              void* d_out, int out_size, void* d_ws, size_t ws_size,
                              hipStream_t stream) {
    const float* x      = (const float*)d_in[0];
    const float* n1g    = (const float*)d_in[1];
    const float* n1b    = (const float*)d_in[2];
    const float* qkv_w  = (const float*)d_in[3];
    const float* qkv_b  = (const float*)d_in[4];
    const float* proj_w = (const float*)d_in[5];
    const float* proj_b = (const float*)d_in[6];
    const float* relh   = (const float*)d_in[7];
    const float* relw   = (const float*)d_in[8];
    const float* n2g    = (const float*)d_in[9];
    const float* n2b    = (const float*)d_in[10];
    const float* w1     = (const float*)d_in[11];
    const float* b1     = (const float*)d_in[12];
    const float* w2     = (const float*)d_in[13];
    const float* b2     = (const float*)d_in[14];
    float* out = (float*)d_out;

    char* ws = (char*)d_ws;
    size_t off = 0;
    auto alloc = [&](size_t bytes) -> void* {
        void* p = ws + off;
        off += (bytes + 255) & ~(size_t)255;
        return p;
    };

    ushort* lnbuf  = (ushort*)alloc((size_t)TOKENS * DIMC * 2);
    ushort* qkvbuf = (ushort*)alloc((size_t)TOKENS * 2304 * 2);
    float* x2      = (float*)alloc((size_t)TOKENS * DIMC * 4);
    ushort* qkvT   = (ushort*)alloc((size_t)2304 * 768 * 2);
    ushort* projT  = (ushort*)alloc((size_t)768 * 768 * 2);
    ushort* w1T    = (ushort*)alloc((size_t)3072 * 768 * 2);
    ushort* w2T    = (ushort*)alloc((size_t)768 * 3072 * 2);
    ushort* aout   = lnbuf;
    ushort* hc     = qkvbuf;

    transpose_k<<<(768 / 32) * (2304 / 32), 256, 0, stream>>>(qkv_w, qkvT, 768, 2304);
    transpose_k<<<(768 / 32) * (768 / 32), 256, 0, stream>>>(proj_w, projT, 768, 768);
    transpose_k<<<(768 / 32) * (3072 / 32), 256, 0, stream>>>(w1, w1T, 768, 3072);
    transpose_k<<<(3072 / 32) * (768 / 32), 256, 0, stream>>>(w2, w2T, 3072, 768);

    ln_k<<<TOKENS, 256, 0, stream>>>(x, n1g, n1b, lnbuf);

    dim3 gq(2304 / 128, TOKENS / 128);
    gemm_k<EPI_BIAS><<<gq, 256, 0, stream>>>(lnbuf, DIMC, qkvT, DIMC, qkv_b, qkvbuf,
                                             nullptr, nullptr, nullptr, 2304, DIMC);

    attn_k<<<100 * NHEADS, 256, 0, stream>>>(qkvbuf, qkv_b, relh, relw, aout);

    dim3 gp(DIMC / 128, TOKENS / 128);
    gemm_k<EPI_PROJRES><<<gp, 256, 0, stream>>>(aout, DIMC, projT, DIMC, proj_b, nullptr,
                                                nullptr, x, x2, DIMC, DIMC);

    ln_k<<<TOKENS, 256, 0, stream>>>(x2, n2g, n2b, lnbuf);

    dim3 gh(1536 / 128, TOKENS / 128);
    for (int c = 0; c < 2; ++c) {
        gemm_k<EPI_GELU><<<gh, 256, 0, stream>>>(lnbuf, DIMC, w1T + (size_t)c * 1536 * 768, DIMC,
                                                 b1 + c * 1536, hc, nullptr, nullptr, nullptr,
                                                 1536, DIMC);
        if (c == 0)
            gemm_k<EPI_ACC><<<gp, 256, 0, stream>>>(hc, 1536, w2T + (size_t)c * 1536, 3072,
                                                    b2, nullptr, nullptr, nullptr, x2, DIMC, 1536);
        else
            gemm_k<EPI_RESOUT><<<gp, 256, 0, stream>>>(hc, 1536, w2T + (size_t)c * 1536, 3072,
                                                       b2, nullptr, out, nullptr, x2, DIMC, 1536);
    }
}

// Round 9
// 622.471 us; speedup vs baseline: 1.4102x; 1.0618x over previous
//
#include <hip/hip_runtime.h>
#include <hip/hip_bf16.h>
#include <math.h>

#define DIMC 768
#define NHEADS 12
#define WINSZ 14
#define NTOK 196
#define TOKENS 16384

using bf = __hip_bfloat16;
typedef __attribute__((ext_vector_type(4))) float f32x4;
typedef __attribute__((ext_vector_type(8))) short bf16x8;

typedef __attribute__((address_space(3))) void lds_void_t;
typedef const __attribute__((address_space(1))) void gmem_void_t;

__device__ inline float bfu2f(ushort u) { return __uint_as_float((uint)u << 16); }
__device__ inline ushort f2bu(float f) {
    bf t = __float2bfloat16(f);
    return __builtin_bit_cast(ushort, t);
}

// ---------------- weight transpose + fp32 -> bf16 convert, LDS-tiled ----------------
__global__ __launch_bounds__(256) void transpose_k(const float* __restrict__ in,
                                                   ushort* __restrict__ out, int R, int C) {
    __shared__ ushort tile[32][33];
    const int nbx = C >> 5;
    const int bx = blockIdx.x % nbx, by = blockIdx.x / nbx;
    const int tx = threadIdx.x & 31, ty = threadIdx.x >> 5;
#pragma unroll
    for (int p = 0; p < 4; ++p) {
        int r = by * 32 + ty + p * 8;
        tile[ty + p * 8][tx] = f2bu(in[(size_t)r * C + bx * 32 + tx]);
    }
    __syncthreads();
#pragma unroll
    for (int p = 0; p < 4; ++p) {
        int c = bx * 32 + ty + p * 8;
        out[(size_t)c * R + by * 32 + tx] = tile[tx][ty + p * 8];
    }
}

// ---------------- layernorm fp32 in, bf16 out ----------------
__device__ inline float blk_sum(float v, float* wred, int tid) {
    for (int m = 32; m; m >>= 1) v += __shfl_xor(v, m);
    if ((tid & 63) == 0) wred[tid >> 6] = v;
    __syncthreads();
    float r = wred[0] + wred[1] + wred[2] + wred[3];
    __syncthreads();
    return r;
}

__global__ __launch_bounds__(256) void ln_k(const float* __restrict__ x, const float* __restrict__ g,
                                            const float* __restrict__ bb, ushort* __restrict__ out) {
    int row = blockIdx.x, tid = threadIdx.x;
    const float* xr = x + (size_t)row * DIMC;
    __shared__ float wred[4];
    float v0 = xr[tid], v1 = xr[tid + 256], v2 = xr[tid + 512];
    float mean = blk_sum(v0 + v1 + v2, wred, tid) * (1.f / 768.f);
    float d0 = v0 - mean, d1 = v1 - mean, d2 = v2 - mean;
    float var = blk_sum(d0 * d0 + d1 * d1 + d2 * d2, wred, tid) * (1.f / 768.f);
    float rs = rsqrtf(var + 1e-5f);
    ushort* o = out + (size_t)row * DIMC;
    o[tid]       = f2bu(d0 * rs * g[tid]       + bb[tid]);
    o[tid + 256] = f2bu(d1 * rs * g[tid + 256] + bb[tid + 256]);
    o[tid + 512] = f2bu(d2 * rs * g[tid + 512] + bb[tid + 512]);
}

// ---------------- bf16 MFMA GEMM: 128x256 tile, 8 waves (512 thr), BK=32 ring of 3 ----
// M mult of 128, N mult of 256, K mult of 32. Bt pre-transposed [N][K] bf16.
// R8 post-mortem: refilling slot h%3 (the one being consumed) raced slower waves ->
// corruption. FIX: refill at TOP of iter h (after barrier), targeting slot (h+2)%3 =
// (h-1)%3 -- consumed in iter h-1, and all waves finished those reads before arriving
// at barrier(h) (lgkm waits precede the barrier in program order). Depth-2 prefetch:
// at the wait, outstanding <= {stage h, h+1} = 6 loads -> vmcnt(3) leaves h+1 in
// flight; tail vmcnt(0). 8-wave blocks x 2 blocks/CU (72KB) = 4 waves/SIMD.
enum { EPI_BIAS = 0, EPI_GELU = 1, EPI_PROJRES = 2, EPI_ACC = 3, EPI_RESOUT = 4 };

template <int EPI>
__global__ __launch_bounds__(512, 4) void gemm_k(const ushort* __restrict__ A, int lda,
                                                 const ushort* __restrict__ Bt, int ldb,
                                                 const float* __restrict__ bias,
                                                 ushort* __restrict__ outb,
                                                 float* __restrict__ outf,
                                                 const float* __restrict__ xorig,
                                                 float* __restrict__ x2,
                                                 int N, int K) {
    __shared__ ushort hA[3][128 * 32];   // 8 KB each: half-K ring buffers
    __shared__ ushort hB[3][256 * 32];   // 16 KB each

    const int nwg = gridDim.x * gridDim.y;
    const int l = blockIdx.y * gridDim.x + blockIdx.x;
    const int nl = (l & 7) * (nwg >> 3) + (l >> 3);
    const int bx = nl % gridDim.x, by = nl / gridDim.x;
    const int bm = by * 128, bn = bx * 256;

    const int tid = threadIdx.x, wave = tid >> 6, lane = tid & 63;
    const int wy = wave >> 2, wx = wave & 3;       // 2M x 4N wave grid
    const int lm = lane & 15, quad = lane >> 4;

    f32x4 acc[4][4];
#pragma unroll
    for (int r = 0; r < 4; ++r)
#pragma unroll
        for (int s = 0; s < 4; ++s) acc[r][s] = (f32x4){0.f, 0.f, 0.f, 0.f};

    // chunk = 16 rows x 32 cols = 1KB = one gload_lds per wave. A: 8 chunks, B: 16.
    // Wave w stages A chunk w and B chunks 2w, 2w+1 (3 loads per stage).
    // Source col group XOR-permuted: LDS slot (row,g) holds global group g^((row>>1)&3).
    const int srcg = (lane & 3) ^ ((lane >> 3) & 3);
    const ushort* Ab = A + (size_t)(bm + (lane >> 2)) * lda + srcg * 8;
    const ushort* Bb = Bt + (size_t)(bn + (lane >> 2)) * ldb + srcg * 8;
    const size_t a16 = (size_t)16 * lda, b16 = (size_t)16 * ldb;
    const int ca = wave;                 // A chunk
    const int cb0 = wave * 2, cb1 = wave * 2 + 1;

    auto stageH = [&](int bi, int k0) {
        __builtin_amdgcn_global_load_lds((gmem_void_t*)(Ab + (size_t)ca * a16 + k0),
                                         (lds_void_t*)&hA[bi][ca * 512], 16, 0, 0);
        __builtin_amdgcn_global_load_lds((gmem_void_t*)(Bb + (size_t)cb0 * b16 + k0),
                                         (lds_void_t*)&hB[bi][cb0 * 512], 16, 0, 0);
        __builtin_amdgcn_global_load_lds((gmem_void_t*)(Bb + (size_t)cb1 * b16 + k0),
                                         (lds_void_t*)&hB[bi][cb1 * 512], 16, 0, 0);
    };

    const int rg = (quad ^ ((lm >> 1) & 3)) * 8;   // swizzled group for this lane's rows
    const int H = K >> 5;                          // 32-col half-steps

    stageH(0, 0);
    if (H > 1) stageH(1, 32);

    int bi = 0;
    for (int h = 0; h < H; ++h) {
        // wait for stage h to land (own-wave count; cross-wave via the barrier below:
        // every wave passes its own vmcnt first)
        if (h + 1 < H) asm volatile("s_waitcnt vmcnt(3)" ::: "memory");
        else           asm volatile("s_waitcnt vmcnt(0)" ::: "memory");
        __builtin_amdgcn_s_barrier();
        __builtin_amdgcn_sched_barrier(0);

        // refill the slot freed by iter h-1 (all waves' reads of it completed before
        // barrier(h)); writes never alias the slot read in this inter-barrier window
        if (h + 2 < H) stageH((h + 2) % 3, (h + 2) * 32);

        bf16x8 af[4], bv[4];
#pragma unroll
        for (int r = 0; r < 4; ++r)
            af[r] = *(const bf16x8*)&hA[bi][(wy * 64 + r * 16 + lm) * 32 + rg];
#pragma unroll
        for (int s = 0; s < 4; ++s)
            bv[s] = *(const bf16x8*)&hB[bi][(wx * 64 + s * 16 + lm) * 32 + rg];

#pragma unroll
        for (int r = 0; r < 4; ++r)
#pragma unroll
            for (int s = 0; s < 4; ++s)
                acc[r][s] = __builtin_amdgcn_mfma_f32_16x16x32_bf16(af[r], bv[s], acc[r][s], 0, 0, 0);

        bi = (bi == 2) ? 0 : bi + 1;
    }

#pragma unroll
    for (int s = 0; s < 4; ++s) {
        int col = bn + wx * 64 + s * 16 + lm;
        float bvl = (EPI == EPI_ACC) ? 0.f : bias[col];
#pragma unroll
        for (int r = 0; r < 4; ++r) {
#pragma unroll
            for (int i = 0; i < 4; ++i) {
                int row = bm + wy * 64 + r * 16 + quad * 4 + i;
                float v = acc[r][s][i] + bvl;
                size_t idx = (size_t)row * N + col;
                if constexpr (EPI == EPI_BIAS) {
                    outb[idx] = f2bu(v);
                } else if constexpr (EPI == EPI_GELU) {
                    outb[idx] = f2bu(0.5f * v * (1.f + erff(v * 0.70710678118f)));
                } else if constexpr (EPI == EPI_PROJRES) {
                    x2[idx] = xorig[idx] + v;
                } else if constexpr (EPI == EPI_ACC) {
                    x2[idx] += v;
                } else {
                    outf[idx] = x2[idx] + v;
                }
            }
        }
    }
}

// ---------------- MFMA attention: one block per (window, head), 4 waves (R3 proven) ----
__global__ __launch_bounds__(256) void attn_k(const ushort* __restrict__ qkv,
                                              const float* __restrict__ qkvb,
                                              const float* __restrict__ relh,
                                              const float* __restrict__ relw,
                                              ushort* __restrict__ aout) {
    const int win = blockIdx.x / NHEADS, head = blockIdx.x % NHEADS;
    const int b = win / 25, wi = win % 25, wr = wi / 5, wc = wi % 5;
    const int hmax = (wr == 4) ? 8 : WINSZ, wmax = (wc == 4) ? 8 : WINSZ;
    const int hoff = head * 64;
    const int tid = threadIdx.x, wave = tid >> 6, lane = tid & 63;
    const int c = lane & 15, quad = lane >> 4;

    __shared__ ushort Ksw[224 * 64];     // K raw (unscaled), chunk-XOR swizzled (28 KB)
    __shared__ ushort vTs[64 * 264];     // V^T, stride 264 + chunk-XOR swizzle (33 KB)
    __shared__ ushort wscr[4][640];      // per-wave scratch

    // ---- stage K: pure uint4 copy (scale applied in S epilogue) ----
    for (int t = tid; t < 224 * 8; t += 256) {
        int n = t >> 3, ck = t & 7;
        int kh = n >> 4, kw = n & 15;
        uint4 vals;
        if (kw < WINSZ && kh < hmax && kw < wmax) {
            size_t tok = ((size_t)(b * 64 + wr * WINSZ + kh) * 64 + wc * WINSZ + kw);
            vals = *(const uint4*)(qkv + tok * 2304 + 768 + hoff + ck * 8);
        } else if (kw < WINSZ) {  // pad token inside window: k = qkv bias slice
            union { uint4 u; ushort s[8]; } tmp;
#pragma unroll
            for (int j = 0; j < 8; ++j) tmp.s[j] = f2bu(qkvb[768 + hoff + ck * 8 + j]);
            vals = tmp.u;
        } else {
            vals = (uint4){0u, 0u, 0u, 0u};
        }
        *(uint4*)&Ksw[n * 64 + ((ck ^ (n & 7)) * 8)] = vals;
    }
    // ---- stage V^T: coalesced uint4 row reads + swizzled transposed LDS writes ----
    for (int t = tid; t < 224 * 8; t += 256) {
        int n = t >> 3, dg = t & 7;
        int kh = n >> 4, kw = n & 15;
        union { uint4 u; ushort s[8]; } vals;
        if (kw < WINSZ && kh < hmax && kw < wmax) {
            size_t tok = ((size_t)(b * 64 + wr * WINSZ + kh) * 64 + wc * WINSZ + kw);
            vals.u = *(const uint4*)(qkv + tok * 2304 + 1536 + hoff + dg * 8);
        } else if (kw < WINSZ) {
#pragma unroll
            for (int j = 0; j < 8; ++j) vals.s[j] = f2bu(qkvb[1536 + hoff + dg * 8 + j]);
        } else {
            vals.u = (uint4){0u, 0u, 0u, 0u};   // P=0 there; any finite value ok
        }
        int kchunk = n >> 3;
#pragma unroll
        for (int j = 0; j < 8; ++j) {
            int d = dg * 8 + j;
            vTs[d * 264 + ((kchunk ^ dg) * 8) + (n & 7)] = vals.s[j];
        }
    }
    __syncthreads();   // the ONLY block barrier

    bf16x8 rhB[2][2], rwB[2][2];
#pragma unroll
    for (int nt = 0; nt < 2; ++nt) {
        int j = nt * 16 + c; if (j > 26) j = 26;
#pragma unroll
        for (int ks = 0; ks < 2; ++ks) {
            const float* ph = relh + (size_t)j * 64 + ks * 32 + quad * 8;
            const float* pw = relw + (size_t)j * 64 + ks * 32 + quad * 8;
            bf16x8 h, w;
#pragma unroll
            for (int e = 0; e < 8; ++e) {
                h[e] = (short)f2bu(ph[e]);
                w[e] = (short)f2bu(pw[e]);
            }
            rhB[nt][ks] = h; rwB[nt][ks] = w;
        }
    }

    ushort* scr = &wscr[wave][0];
    const int lane48 = lane & 48;

    for (int qh = wave; qh < hmax; qh += 4) {
        int qw = c < wmax ? c : (wmax - 1);
        size_t qtok = ((size_t)(b * 64 + wr * WINSZ + qh) * 64 + wc * WINSZ + qw);
        bf16x8 aq0 = *(const bf16x8*)(qkv + qtok * 2304 + hoff + quad * 8);
        bf16x8 aq1 = *(const bf16x8*)(qkv + qtok * 2304 + hoff + 32 + quad * 8);

        f32x4 z = (f32x4){0.f, 0.f, 0.f, 0.f};
        f32x4 dh0 = __builtin_amdgcn_mfma_f32_16x16x32_bf16(aq0, rhB[0][0], z, 0, 0, 0);
        dh0 = __builtin_amdgcn_mfma_f32_16x16x32_bf16(aq1, rhB[0][1], dh0, 0, 0, 0);
        f32x4 dh1 = __builtin_amdgcn_mfma_f32_16x16x32_bf16(aq0, rhB[1][0], z, 0, 0, 0);
        dh1 = __builtin_amdgcn_mfma_f32_16x16x32_bf16(aq1, rhB[1][1], dh1, 0, 0, 0);
        f32x4 dw0 = __builtin_amdgcn_mfma_f32_16x16x32_bf16(aq0, rwB[0][0], z, 0, 0, 0);
        dw0 = __builtin_amdgcn_mfma_f32_16x16x32_bf16(aq1, rwB[0][1], dw0, 0, 0, 0);
        f32x4 dw1 = __builtin_amdgcn_mfma_f32_16x16x32_bf16(aq0, rwB[1][0], z, 0, 0, 0);
        dw1 = __builtin_amdgcn_mfma_f32_16x16x32_bf16(aq1, rwB[1][1], dw1, 0, 0, 0);

#pragma unroll
        for (int i = 0; i < 4; ++i) {
            scr[(quad * 4 + i) * 28 + c] = f2bu(dh0[i]);
            if (c < 12) scr[(quad * 4 + i) * 28 + 16 + c] = f2bu(dh1[i]);
        }

        float bw[4];
#pragma unroll
        for (int i = 0; i < 4; ++i) {
            int m = quad * 4 + i;
            int j = m - c + 13; int jc = j < 0 ? 0 : j;
            int addr = (lane48 | (jc & 15)) << 2;
            int t0 = __builtin_amdgcn_ds_bpermute(addr, __float_as_int(dw0[i]));
            int t1 = __builtin_amdgcn_ds_bpermute(addr, __float_as_int(dw1[i]));
            bw[i] = (jc >= 16) ? __int_as_float(t1) : __int_as_float(t0);
        }

        f32x4 s[14];
#pragma unroll
        for (int kh = 0; kh < 14; ++kh) {
            int n = kh * 16 + c;
            int n7 = n & 7;
            bf16x8 kb0 = *(const bf16x8*)&Ksw[n * 64 + ((0 * 4 + quad) ^ n7) * 8];
            bf16x8 kb1 = *(const bf16x8*)&Ksw[n * 64 + ((1 * 4 + quad) ^ n7) * 8];
            f32x4 acc = __builtin_amdgcn_mfma_f32_16x16x32_bf16(aq0, kb0, z, 0, 0, 0);
            acc = __builtin_amdgcn_mfma_f32_16x16x32_bf16(aq1, kb1, acc, 0, 0, 0);
            int jstar = qh + 13 - kh;
#pragma unroll
            for (int i = 0; i < 4; ++i) {
                float dh = bfu2f(scr[(quad * 4 + i) * 28 + jstar]);
                float v = fmaf(0.125f, acc[i], dh + bw[i]);
                acc[i] = (c < WINSZ) ? v : -1e30f;
            }
            s[kh] = acc;
        }

        float inv[4];
#pragma unroll
        for (int i = 0; i < 4; ++i) {
            float mx = s[0][i];
#pragma unroll
            for (int kh = 1; kh < 14; ++kh) mx = fmaxf(mx, s[kh][i]);
            mx = fmaxf(mx, __shfl_xor(mx, 1));
            mx = fmaxf(mx, __shfl_xor(mx, 2));
            mx = fmaxf(mx, __shfl_xor(mx, 4));
            mx = fmaxf(mx, __shfl_xor(mx, 8));
            float sum = 0.f;
#pragma unroll
            for (int kh = 0; kh < 14; ++kh) {
                float e = __expf(s[kh][i] - mx);
                s[kh][i] = e;
                sum += e;
            }
            sum += __shfl_xor(sum, 1);
            sum += __shfl_xor(sum, 2);
            sum += __shfl_xor(sum, 4);
            sum += __shfl_xor(sum, 8);
            inv[i] = 1.f / sum;
        }

        f32x4 o[4] = {z, z, z, z};
#pragma unroll
        for (int cc = 0; cc < 7; ++cc) {
#pragma unroll
            for (int i = 0; i < 4; ++i) {
                scr[(quad * 4 + i) * 40 + c]      = f2bu(s[2 * cc][i] * inv[i]);
                scr[(quad * 4 + i) * 40 + 16 + c] = f2bu(s[2 * cc + 1][i] * inv[i]);
            }
            bf16x8 ap = *(const bf16x8*)&scr[c * 40 + quad * 8];
#pragma unroll
            for (int vt = 0; vt < 4; ++vt) {
                int d = vt * 16 + c;
                int dgr = (d >> 3) & 7;
                bf16x8 vb = *(const bf16x8*)&vTs[d * 264 + (((cc * 4 + quad) ^ dgr) * 8)];
                o[vt] = __builtin_amdgcn_mfma_f32_16x16x32_bf16(ap, vb, o[vt], 0, 0, 0);
            }
        }

#pragma unroll
        for (int i = 0; i < 4; ++i) {
            int qwp = quad * 4 + i;
            if (qwp < wmax) {
                size_t otok = ((size_t)(b * 64 + wr * WINSZ + qh) * 64 + wc * WINSZ + qwp);
#pragma unroll
                for (int vt = 0; vt < 4; ++vt)
                    aout[otok * 768 + hoff + vt * 16 + c] = f2bu(o[vt][i]);
            }
        }
    }
}

extern "C" void kernel_launch(void* const* d_in, const int* in_sizes, int n_in,
                              void* d_out, int out_size, void* d_ws, size_t ws_size,
                              hipStream_t stream) {
    const float* x      = (const float*)d_in[0];
    const float* n1g    = (const float*)d_in[1];
    const float* n1b    = (const float*)d_in[2];
    const float* qkv_w  = (const float*)d_in[3];
    const float* qkv_b  = (const float*)d_in[4];
    const float* proj_w = (const float*)d_in[5];
    const float* proj_b = (const float*)d_in[6];
    const float* relh   = (const float*)d_in[7];
    const float* relw   = (const float*)d_in[8];
    const float* n2g    = (const float*)d_in[9];
    const float* n2b    = (const float*)d_in[10];
    const float* w1     = (const float*)d_in[11];
    const float* b1     = (const float*)d_in[12];
    const float* w2     = (const float*)d_in[13];
    const float* b2     = (const float*)d_in[14];
    float* out = (float*)d_out;

    char* ws = (char*)d_ws;
    size_t off = 0;
    auto alloc = [&](size_t bytes) -> void* {
        void* p = ws + off;
        off += (bytes + 255) & ~(size_t)255;
        return p;
    };

    ushort* lnbuf  = (ushort*)alloc((size_t)TOKENS * DIMC * 2);
    ushort* qkvbuf = (ushort*)alloc((size_t)TOKENS * 2304 * 2);
    float* x2      = (float*)alloc((size_t)TOKENS * DIMC * 4);
    ushort* qkvT   = (ushort*)alloc((size_t)2304 * 768 * 2);
    ushort* projT  = (ushort*)alloc((size_t)768 * 768 * 2);
    ushort* w1T    = (ushort*)alloc((size_t)3072 * 768 * 2);
    ushort* w2T    = (ushort*)alloc((size_t)768 * 3072 * 2);
    ushort* aout   = lnbuf;
    ushort* hc     = qkvbuf;

    transpose_k<<<(768 / 32) * (2304 / 32), 256, 0, stream>>>(qkv_w, qkvT, 768, 2304);
    transpose_k<<<(768 / 32) * (768 / 32), 256, 0, stream>>>(proj_w, projT, 768, 768);
    transpose_k<<<(768 / 32) * (3072 / 32), 256, 0, stream>>>(w1, w1T, 768, 3072);
    transpose_k<<<(3072 / 32) * (768 / 32), 256, 0, stream>>>(w2, w2T, 3072, 768);

    ln_k<<<TOKENS, 256, 0, stream>>>(x, n1g, n1b, lnbuf);

    dim3 gq(2304 / 256, TOKENS / 128);
    gemm_k<EPI_BIAS><<<gq, 512, 0, stream>>>(lnbuf, DIMC, qkvT, DIMC, qkv_b, qkvbuf,
                                             nullptr, nullptr, nullptr, 2304, DIMC);

    attn_k<<<100 * NHEADS, 256, 0, stream>>>(qkvbuf, qkv_b, relh, relw, aout);

    dim3 gp(DIMC / 256, TOKENS / 128);
    gemm_k<EPI_PROJRES><<<gp, 512, 0, stream>>>(aout, DIMC, projT, DIMC, proj_b, nullptr,
                                                nullptr, x, x2, DIMC, DIMC);

    ln_k<<<TOKENS, 256, 0, stream>>>(x2, n2g, n2b, lnbuf);

    dim3 gh(1536 / 256, TOKENS / 128);
    for (int c = 0; c < 2; ++c) {
        gemm_k<EPI_GELU><<<gh, 512, 0, stream>>>(lnbuf, DIMC, w1T + (size_t)c * 1536 * 768, DIMC,
                                                 b1 + c * 1536, hc, nullptr, nullptr, nullptr,
                                                 1536, DIMC);
        if (c == 0)
            gemm_k<EPI_ACC><<<gp, 512, 0, stream>>>(hc, 1536, w2T + (size_t)c * 1536, 3072,
                                                    b2, nullptr, nullptr, nullptr, x2, DIMC, 1536);
        else
            gemm_k<EPI_RESOUT><<<gp, 512, 0, stream>>>(hc, 1536, w2T + (size_t)c * 1536, 3072,
                                                       b2, nullptr, out, nullptr, x2, DIMC, 1536);
    }
}